// Round 8
// baseline (4331.159 us; speedup 1.0000x reference)
//
#include <hip/hip_runtime.h>
#include <stdint.h>

// ---------------------------------------------------------------------------
// MarketScoringUnit: LSTM(B=128,T=512,H=512) + attention + (mu, sigma) head.
// Round 8 lstm_rec: R7 structure (in-lane gates, 8 producers per bg, W_hh in
// VGPRs) x R6 trick (2-way batch-group interleave). 32 WGs = 4 pairs x 8
// hid-groups; each WG runs TWO independent bg chains with the same weights,
// alternating poll->MFMA->publish so each tile's exchange latency hides
// under the other tile's compute. Eager tagged data-poll exchange.
// ---------------------------------------------------------------------------

using short8  = __attribute__((ext_vector_type(8))) short;   // 8 bf16 (4 VGPRs)
using short4v = __attribute__((ext_vector_type(4))) short;
using floatx4 = __attribute__((ext_vector_type(4))) float;

#define MFMA16(a, b, c) __builtin_amdgcn_mfma_f32_16x16x32_bf16((a), (b), (c), 0, 0, 0)

__device__ __forceinline__ unsigned short f2b(float f) {
    unsigned u = __float_as_uint(f);
    u += 0x7FFFu + ((u >> 16) & 1u);           // RNE
    return (unsigned short)(u >> 16);
}
__device__ __forceinline__ float b2f(unsigned short h) {
    return __uint_as_float(((unsigned)h) << 16);
}
__device__ __forceinline__ float sigm(float x) { return 1.0f / (1.0f + __expf(-x)); }
__device__ __forceinline__ float tanh_(float x) { return 1.0f - 2.0f / (__expf(2.0f * x) + 1.0f); }

// ---------------------------------------------------------------------------
// prep: fp32 -> bf16 conversions, U1 split into U1a/U1b, bias = b_ih + b_hh
// ---------------------------------------------------------------------------
__global__ __launch_bounds__(256) void prep(
    const float* __restrict__ x, const float* __restrict__ Wih, const float* __restrict__ Whh,
    const float* __restrict__ bih, const float* __restrict__ bhh,
    const float* __restrict__ U1, const float* __restrict__ U2,
    unsigned short* __restrict__ x_bf, unsigned short* __restrict__ Wih_bf,
    unsigned short* __restrict__ Whh_bf, unsigned short* __restrict__ U1a,
    unsigned short* __restrict__ U1b, unsigned short* __restrict__ U2b,
    float* __restrict__ bias)
{
    const long long NX4 = 33554432LL / 4;  // x as float4
    const long long NREST = 1048576LL + 1048576LL + 524288LL + 262144LL + 2048LL;
    const long long total = NX4 + NREST;
    for (long long u = (long long)blockIdx.x * 256 + threadIdx.x; u < total;
         u += (long long)gridDim.x * 256) {
        if (u < NX4) {
            float4 v = ((const float4*)x)[u];
            short4v o;
            o[0] = (short)f2b(v.x); o[1] = (short)f2b(v.y);
            o[2] = (short)f2b(v.z); o[3] = (short)f2b(v.w);
            *(short4v*)&x_bf[u * 4] = o;
        } else {
            long long i = u - NX4;
            if (i < 1048576) { Wih_bf[i] = f2b(Wih[i]); continue; }
            i -= 1048576;
            if (i < 1048576) { Whh_bf[i] = f2b(Whh[i]); continue; }
            i -= 1048576;
            if (i < 524288) {
                int row = (int)(i >> 10), col = (int)(i & 1023);
                if (col < 512) U1a[row * 512 + col] = f2b(U1[i]);
                else           U1b[row * 512 + (col - 512)] = f2b(U1[i]);
                continue;
            }
            i -= 524288;
            if (i < 262144) { U2b[i] = f2b(U2[i]); continue; }
            i -= 262144;
            bias[i] = bih[i] + bhh[i];
        }
    }
}

// ---------------------------------------------------------------------------
// gemm_bt: C[m][n] = sum_k A[m][k]*B[n][k] (+bias[n]); bf16 in/out, fp32 acc.
// 128x128 block tile, BK=64, 4 waves of 64x64.
// mode==1: scatter-store into xg layout [t][jg][b][c], c = gate*16 + (n&15),
//          jg = (n>>4)&31, gate = n>>9  (tile rows = 128 consecutive t, one b)
// ---------------------------------------------------------------------------
__global__ __launch_bounds__(256) void gemm_bt(
    const unsigned short* __restrict__ A, long long lda,
    const unsigned short* __restrict__ Bm, long long ldb,
    unsigned short* __restrict__ C, long long ldc,
    const float* __restrict__ bias, int mode)
{
    __shared__ __align__(16) unsigned short sbuf[2 * 128 * 72];
    unsigned short* At = sbuf;
    unsigned short* Bt = sbuf + 128 * 72;
    unsigned short* Ct = sbuf;  // alias, used after final sync

    const int m0 = blockIdx.x * 128, n0 = blockIdx.y * 128;
    const int tid = threadIdx.x;
    const int wv = tid >> 6, lane = tid & 63, l15 = lane & 15, q = lane >> 4;
    const int wm = wv & 1, wn = wv >> 1;

    floatx4 acc[4][4];
    for (int i = 0; i < 4; i++)
        for (int j = 0; j < 4; j++) acc[i][j] = (floatx4){0.f, 0.f, 0.f, 0.f};

    for (int k0 = 0; k0 < 512; k0 += 64) {
        for (int p = 0; p < 4; p++) {
            int idx = tid + p * 256;
            int row = idx >> 3, ch = idx & 7;
            *(short8*)&At[row * 72 + ch * 8] =
                *(const short8*)&A[(long long)(m0 + row) * lda + k0 + ch * 8];
            *(short8*)&Bt[row * 72 + ch * 8] =
                *(const short8*)&Bm[(long long)(n0 + row) * ldb + k0 + ch * 8];
        }
        __syncthreads();
        for (int ks = 0; ks < 64; ks += 32) {
            short8 af[4], bfv[4];
            for (int mi = 0; mi < 4; mi++)
                af[mi] = *(const short8*)&At[(wm * 64 + mi * 16 + l15) * 72 + ks + q * 8];
            for (int ni = 0; ni < 4; ni++)
                bfv[ni] = *(const short8*)&Bt[(wn * 64 + ni * 16 + l15) * 72 + ks + q * 8];
            for (int mi = 0; mi < 4; mi++)
                for (int ni = 0; ni < 4; ni++)
                    acc[mi][ni] = MFMA16(af[mi], bfv[ni], acc[mi][ni]);
        }
        __syncthreads();
    }

    float bv[4];
    for (int ni = 0; ni < 4; ni++)
        bv[ni] = bias ? bias[n0 + wn * 64 + ni * 16 + l15] : 0.0f;

    for (int mi = 0; mi < 4; mi++)
        for (int ni = 0; ni < 4; ni++)
            for (int r = 0; r < 4; r++)
                Ct[(wm * 64 + mi * 16 + q * 4 + r) * 128 + wn * 64 + ni * 16 + l15] =
                    f2b(acc[mi][ni][r] + bv[ni]);
    __syncthreads();

    const int tt0 = m0 & 511, bglob = m0 >> 9;
    for (int p = 0; p < 8; p++) {
        int idx = tid + p * 256;
        int row = idx >> 4, ch = idx & 15;
        if (mode) {
            int n = n0 + ch * 8;
            int gate = n >> 9, jg = (n >> 4) & 31, c0 = gate * 16 + (n & 15);
            long long dst = (((long long)(tt0 + row) * 32 + jg) * 128 + bglob) * 64 + c0;
            *(short8*)&C[dst] = *(const short8*)&Ct[row * 128 + ch * 8];
        } else {
            *(short8*)&C[(long long)(m0 + row) * ldc + n0 + ch * 8] =
                *(const short8*)&Ct[row * 128 + ch * 8];
        }
    }
}

// ---------------------------------------------------------------------------
// lstm_rec: 32 WGs = 4 bg-pairs x 8 hid-groups; 2-way bg interleave.
// Wave wv of WG (pair,jgb) owns hid = jgb*64 + wv*16 + l15 for ALL 4 GATES
// (Wreg[ct][kk] in VGPRs, shared by both bg tiles), batches q*4+r per tile.
// Per step: [poll A -> stage -> MFMA A -> pointwise -> publish A] then B;
// each tile's publish/visibility hides under the other tile's work.
// Exchange: 2-slot tagged ring, eager all-lane 64-bit relaxed-atomic poll.
// ---------------------------------------------------------------------------
__global__ __launch_bounds__(256, 1) void lstm_rec(
    const unsigned short* __restrict__ xg,   // [t][jg32][b][c]  c = gate*16+hl
    const unsigned short* __restrict__ Whh,  // (2048, 512) bf16
    unsigned short* __restrict__ h_all,      // [b][t][h]  (128, 512, 512)
    unsigned int* __restrict__ ring)         // [2][128][512] tagged words
{
    __shared__ unsigned int At[2][16 * 264];  // one buffer per tile (A/B)

    const int tid = threadIdx.x;
    const int wv = tid >> 6, lane = tid & 63, l15 = lane & 15, q = lane >> 4;
    const int pair = blockIdx.x >> 3, jgb = blockIdx.x & 7;
    const int jg32 = jgb * 4 + wv;            // 16-hid group of this wave
    const int hid = jg32 * 16 + l15;          // this lane's hidden index

    // W_hh B-frags: Wreg[ct][kk], row = ct*512 + hid, k = kk*32 + q*8
    short8 Wreg[4][16];
    #pragma unroll
    for (int ct = 0; ct < 4; ct++)
        #pragma unroll
        for (int kk = 0; kk < 16; kk++)
            Wreg[ct][kk] = *(const short8*)
                &Whh[(long long)(ct * 512 + hid) * 512 + kk * 32 + q * 8];

    float cst[2][4] = {{0.f, 0.f, 0.f, 0.f}, {0.f, 0.f, 0.f, 0.f}};

    for (int t = 0; t < 512; t++) {
        // ---- prefetch xg for BOTH tiles (independent of h) ----
        float xv[2][16];
        #pragma unroll
        for (int hf = 0; hf < 2; hf++) {
            const int b0 = (pair + hf * 4) * 16;
            const long long xbase = ((long long)(t * 32 + jg32) * 128 + b0) * 64;
            #pragma unroll
            for (int ct = 0; ct < 4; ct++)
                #pragma unroll
                for (int r = 0; r < 4; r++)
                    xv[hf][ct * 4 + r] =
                        b2f(xg[xbase + (q * 4 + r) * 64 + ct * 16 + l15]);
        }

        #pragma unroll
        for (int hf = 0; hf < 2; hf++) {
            const int b0 = (pair + hf * 4) * 16;
            floatx4 acc[4];
            #pragma unroll
            for (int ct = 0; ct < 4; ct++)
                #pragma unroll
                for (int r = 0; r < 4; r++)
                    acc[ct][r] = xv[hf][ct * 4 + r];

            if (t > 0) {
                const unsigned want = (unsigned)(t - 1);
                const int sl = (t - 1) & 1;
                unsigned long long* rb = (unsigned long long*)
                    (ring + sl * 65536 + b0 * 512);
                unsigned long long w[16];
                #pragma unroll
                for (int i = 0; i < 16; i++)
                    w[i] = __hip_atomic_load(&rb[tid + i * 256], __ATOMIC_RELAXED,
                                             __HIP_MEMORY_SCOPE_AGENT);
                while (true) {
                    unsigned bad = 0;
                    #pragma unroll
                    for (int i = 0; i < 16; i++) {
                        unsigned lo = (unsigned)(w[i] >> 16) & 0xFFFFu;
                        unsigned hi = (unsigned)(w[i] >> 48);
                        bad |= (lo ^ want) | (hi ^ want);
                    }
                    if (!bad) break;
                    #pragma unroll
                    for (int i = 0; i < 16; i++) {
                        unsigned lo = (unsigned)(w[i] >> 16) & 0xFFFFu;
                        unsigned hi = (unsigned)(w[i] >> 48);
                        if ((lo ^ want) | (hi ^ want))
                            w[i] = __hip_atomic_load(&rb[tid + i * 256], __ATOMIC_RELAXED,
                                                     __HIP_MEMORY_SCOPE_AGENT);
                    }
                }
                // strip tags, pack two bf16 per LDS word
                unsigned int* dst = &At[hf][0];
                #pragma unroll
                for (int i = 0; i < 16; i++) {
                    int idx = tid + i * 256;
                    int row = idx >> 8, k = idx & 255;
                    dst[row * 264 + k] =
                        (unsigned)(w[i] & 0xFFFFu) | ((unsigned)(w[i] >> 32) << 16);
                }
                __syncthreads();
                // MFMA: A = h tile (batch l15, K), B = Wreg; 4 chains (1/gate)
                const unsigned int* ap = &At[hf][l15 * 264 + q * 4];
                #pragma unroll
                for (int kk = 0; kk < 16; kk++) {
                    short8 af = *(const short8*)(ap + kk * 16);
                    acc[0] = MFMA16(af, Wreg[0][kk], acc[0]);
                    acc[1] = MFMA16(af, Wreg[1][kk], acc[1]);
                    acc[2] = MFMA16(af, Wreg[2][kk], acc[2]);
                    acc[3] = MFMA16(af, Wreg[3][kk], acc[3]);
                }
            }
            // ---- pointwise: gates in-lane (acc[0..3] = i,f,g,o) ----
            unsigned short hbv[4];
            #pragma unroll
            for (int r = 0; r < 4; r++) {
                float ig = sigm(acc[0][r]);
                float fg = sigm(acc[1][r]);
                float gv = tanh_(acc[2][r]);
                float og = sigm(acc[3][r]);
                cst[hf][r] = fg * cst[hf][r] + ig * gv;
                hbv[r] = f2b(og * tanh_(cst[hf][r]));
            }
            // publish: ring first (latency-critical), then h_all
            #pragma unroll
            for (int r = 0; r < 4; r++) {
                const int b = b0 + q * 4 + r;
                __hip_atomic_store(&ring[(t & 1) * 65536 + b * 512 + hid],
                                   ((unsigned)t << 16) | hbv[r], __ATOMIC_RELAXED,
                                   __HIP_MEMORY_SCOPE_AGENT);
            }
            #pragma unroll
            for (int r = 0; r < 4; r++) {
                const int b = b0 + q * 4 + r;
                h_all[(long long)b * 262144 + (long long)t * 512 + hid] = hbv[r];
            }
        }
    }
}

// ---------------------------------------------------------------------------
// attn_e: e[b,t] = Ve . tanh(h@U1a^T + u1b[b] + x@U2^T), fused, 32 t per WG.
// ---------------------------------------------------------------------------
__global__ __launch_bounds__(256) void attn_e(
    const unsigned short* __restrict__ h_all,
    const unsigned short* __restrict__ x_bf,
    const unsigned short* __restrict__ U1a, const unsigned short* __restrict__ U2b,
    const unsigned short* __restrict__ u1b,  // bf16 (128,512)
    const float* __restrict__ Ve,
    float* __restrict__ e)
{
    __shared__ __align__(16) unsigned short Bt[512 * 40];
    __shared__ __align__(16) unsigned short At[32 * 40];
    __shared__ float ered[4][32];

    const int tid = threadIdx.x;
    const int wv = tid >> 6, lane = tid & 63, l15 = lane & 15, q = lane >> 4;
    const int b = blockIdx.x >> 4, t0 = (blockIdx.x & 15) * 32;

    floatx4 acc[2][8];
    for (int mi = 0; mi < 2; mi++)
        for (int ni = 0; ni < 8; ni++) acc[mi][ni] = (floatx4){0.f, 0.f, 0.f, 0.f};

    for (int it = 0; it < 32; it++) {
        const int phase = it >> 4, kk = (it & 15) * 32;
        const unsigned short* Asrc = phase ? x_bf : h_all;
        const unsigned short* Bsrc = phase ? U2b : U1a;
        __syncthreads();
        for (int idx = tid; idx < 2048; idx += 256) {
            int row = idx >> 2, ch = idx & 3;
            *(short8*)&Bt[row * 40 + ch * 8] =
                *(const short8*)&Bsrc[(long long)row * 512 + kk + ch * 8];
        }
        if (tid < 128) {
            int row = tid >> 2, ch = tid & 3;
            *(short8*)&At[row * 40 + ch * 8] =
                *(const short8*)&Asrc[(long long)(b * 512 + t0 + row) * 512 + kk + ch * 8];
        }
        __syncthreads();
        short8 af[2];
        for (int mi = 0; mi < 2; mi++)
            af[mi] = *(const short8*)&At[(mi * 16 + l15) * 40 + q * 8];
        for (int ni = 0; ni < 8; ni++) {
            short8 bfv = *(const short8*)&Bt[(wv * 128 + ni * 16 + l15) * 40 + q * 8];
            acc[0][ni] = MFMA16(af[0], bfv, acc[0][ni]);
            acc[1][ni] = MFMA16(af[1], bfv, acc[1][ni]);
        }
    }

    float s[2][4] = {{0.f, 0.f, 0.f, 0.f}, {0.f, 0.f, 0.f, 0.f}};
    for (int ni = 0; ni < 8; ni++) {
        int n = wv * 128 + ni * 16 + l15;
        float ub = b2f(u1b[b * 512 + n]);
        float vev = Ve[n];
        for (int mi = 0; mi < 2; mi++)
            for (int r = 0; r < 4; r++)
                s[mi][r] += vev * tanh_(acc[mi][ni][r] + ub);
    }
    for (int off = 1; off <= 8; off <<= 1)
        for (int mi = 0; mi < 2; mi++)
            for (int r = 0; r < 4; r++) s[mi][r] += __shfl_xor(s[mi][r], off);
    if (l15 == 0)
        for (int mi = 0; mi < 2; mi++)
            for (int r = 0; r < 4; r++) ered[wv][mi * 16 + q * 4 + r] = s[mi][r];
    __syncthreads();
    if (tid < 32)
        e[(long long)b * 512 + t0 + tid] =
            ered[0][tid] + ered[1][tid] + ered[2][tid] + ered[3][tid];
}

// ---------------------------------------------------------------------------
// attn_out: softmax over T, context = alpha.h, head -> mu, sigma. 1 WG per b.
// ---------------------------------------------------------------------------
__global__ __launch_bounds__(256) void attn_out(
    const float* __restrict__ e, const unsigned short* __restrict__ h_all,
    const float* __restrict__ Wout, const float* __restrict__ bout,
    float* __restrict__ outp)
{
    __shared__ float sm[512];
    __shared__ float red[8];
    const int b = blockIdx.x, tid = threadIdx.x;
    const int wv = tid >> 6, lane = tid & 63;

    float e0 = e[b * 512 + tid], e1 = e[b * 512 + 256 + tid];
    float mx = fmaxf(e0, e1);
    for (int off = 32; off; off >>= 1) mx = fmaxf(mx, __shfl_xor(mx, off));
    if (lane == 0) red[wv] = mx;
    __syncthreads();
    mx = fmaxf(fmaxf(red[0], red[1]), fmaxf(red[2], red[3]));

    float s0 = __expf(e0 - mx), s1 = __expf(e1 - mx);
    sm[tid] = s0; sm[256 + tid] = s1;
    float ss = s0 + s1;
    for (int off = 32; off; off >>= 1) ss += __shfl_xor(ss, off);
    if (lane == 0) red[4 + wv] = ss;
    __syncthreads();
    float inv = 1.0f / (red[4] + red[5] + red[6] + red[7]);

    const long long base = (long long)b * 262144;
    float a0 = 0.f, a1 = 0.f;
    for (int t = 0; t < 512; t++) {
        float al = sm[t];
        a0 += al * b2f(h_all[base + t * 512 + tid]);
        a1 += al * b2f(h_all[base + t * 512 + 256 + tid]);
    }
    a0 *= inv; a1 *= inv;

    float q0 = a0 * Wout[tid] + a1 * Wout[256 + tid];
    float q1 = a0 * Wout[512 + tid] + a1 * Wout[768 + tid];
    for (int off = 32; off; off >>= 1) { q0 += __shfl_xor(q0, off); q1 += __shfl_xor(q1, off); }
    __syncthreads();  // red reuse
    if (lane == 0) { red[wv] = q0; red[4 + wv] = q1; }
    __syncthreads();
    if (tid == 0) {
        float P0 = red[0] + red[1] + red[2] + red[3] + bout[0];
        float P1 = red[4] + red[5] + red[6] + red[7] + bout[1];
        outp[b] = P0;
        float sp = (P1 > 15.0f) ? P1 : log1pf(__expf(P1));
        outp[128 + b] = sp + 1e-5f;
    }
}

// ---------------------------------------------------------------------------
extern "C" void kernel_launch(void* const* d_in, const int* in_sizes, int n_in,
                              void* d_out, int out_size, void* d_ws, size_t ws_size,
                              hipStream_t stream)
{
    const float* x    = (const float*)d_in[0];
    const float* Wih  = (const float*)d_in[1];
    const float* Whh  = (const float*)d_in[2];
    const float* bih  = (const float*)d_in[3];
    const float* bhh  = (const float*)d_in[4];
    const float* Ve   = (const float*)d_in[5];
    const float* U1   = (const float*)d_in[6];
    const float* U2   = (const float*)d_in[7];
    const float* Wout = (const float*)d_in[8];
    const float* bout = (const float*)d_in[9];
    float* out = (float*)d_out;

    char* ws = (char*)d_ws;
    size_t off = 0;
    auto alloc = [&](size_t bytes) -> void* {
        void* p = ws + off;
        off += (bytes + 255) & ~(size_t)255;
        return p;
    };
    unsigned short* x_bf   = (unsigned short*)alloc(33554432ull * 2);
    unsigned short* Wih_bf = (unsigned short*)alloc(1048576ull * 2);
    unsigned short* Whh_bf = (unsigned short*)alloc(1048576ull * 2);
    unsigned short* U1a    = (unsigned short*)alloc(262144ull * 2);
    unsigned short* U1b    = (unsigned short*)alloc(262144ull * 2);
    unsigned short* U2b    = (unsigned short*)alloc(262144ull * 2);
    float*          bias   = (float*)alloc(2048ull * 4);
    unsigned short* xg     = (unsigned short*)alloc(134217728ull * 2);
    unsigned short* h_all  = (unsigned short*)alloc(33554432ull * 2);
    unsigned short* u1bv   = (unsigned short*)alloc(65536ull * 2);
    float*          e      = (float*)alloc(65536ull * 4);
    unsigned int*   ring   = (unsigned int*)alloc(131072ull * 4);  // 2x128x512 tagged
    if (off > ws_size) return;  // workspace too small: fail safe (no corruption)

    prep<<<4096, 256, 0, stream>>>(x, Wih, Whh, bih, bhh, U1, U2,
                                   x_bf, Wih_bf, Whh_bf, U1a, U1b, U2b, bias);
    // xg = x @ W_ih^T + b, scattered into [t][jg][b][c]
    gemm_bt<<<dim3(512, 16), 256, 0, stream>>>(x_bf, 512, Wih_bf, 512,
                                               xg, 2048, bias, 1);
    lstm_rec<<<32, 256, 0, stream>>>(xg, Whh_bf, h_all, ring);
    // u1b = h_last @ U1b^T
    gemm_bt<<<dim3(1, 4), 256, 0, stream>>>(h_all + 511 * 512, 262144, U1b, 512,
                                            u1bv, 512, nullptr, 0);
    attn_e<<<2048, 256, 0, stream>>>(h_all, x_bf, U1a, U2b, u1bv, Ve, e);
    attn_out<<<128, 256, 0, stream>>>(e, h_all, Wout, bout, out);
}

// Round 9
// 3765.953 us; speedup vs baseline: 1.1501x; 1.1501x over previous
//
#include <hip/hip_runtime.h>
#include <stdint.h>

// ---------------------------------------------------------------------------
// MarketScoringUnit: LSTM(B=128,T=512,H=512) + attention + (mu, sigma) head.
// Round 9 lstm_rec: R7 structure (64 WGs, in-lane gates, W_hh in VGPRs/AGPRs)
// with the ring poll rebuilt as ONE inline-asm burst: 8x global_load_dwordx4
// (sc0 sc1 = L1+L2 bypass, coherent) + a single s_waitcnt vmcnt(0). Theory:
// __hip_atomic_load sequences were issued/waited quasi-serially (~16 RTTs
// ~2.6us fixed poll cost); one pipelined burst costs ~1 RTT. Retries (rare,
// tag-protected) fall back to 8B atomic loads — no hang risk.
// ---------------------------------------------------------------------------

using short8  = __attribute__((ext_vector_type(8))) short;   // 8 bf16 (4 VGPRs)
using short4v = __attribute__((ext_vector_type(4))) short;
using floatx4 = __attribute__((ext_vector_type(4))) float;
using uintx4  = __attribute__((ext_vector_type(4))) unsigned int;

#define MFMA16(a, b, c) __builtin_amdgcn_mfma_f32_16x16x32_bf16((a), (b), (c), 0, 0, 0)

__device__ __forceinline__ unsigned short f2b(float f) {
    unsigned u = __float_as_uint(f);
    u += 0x7FFFu + ((u >> 16) & 1u);           // RNE
    return (unsigned short)(u >> 16);
}
__device__ __forceinline__ float b2f(unsigned short h) {
    return __uint_as_float(((unsigned)h) << 16);
}
__device__ __forceinline__ float sigm(float x) { return 1.0f / (1.0f + __expf(-x)); }
__device__ __forceinline__ float tanh_(float x) { return 1.0f - 2.0f / (__expf(2.0f * x) + 1.0f); }

// ---------------------------------------------------------------------------
// prep: fp32 -> bf16 conversions, U1 split into U1a/U1b, bias = b_ih + b_hh
// ---------------------------------------------------------------------------
__global__ __launch_bounds__(256) void prep(
    const float* __restrict__ x, const float* __restrict__ Wih, const float* __restrict__ Whh,
    const float* __restrict__ bih, const float* __restrict__ bhh,
    const float* __restrict__ U1, const float* __restrict__ U2,
    unsigned short* __restrict__ x_bf, unsigned short* __restrict__ Wih_bf,
    unsigned short* __restrict__ Whh_bf, unsigned short* __restrict__ U1a,
    unsigned short* __restrict__ U1b, unsigned short* __restrict__ U2b,
    float* __restrict__ bias)
{
    const long long NX4 = 33554432LL / 4;  // x as float4
    const long long NREST = 1048576LL + 1048576LL + 524288LL + 262144LL + 2048LL;
    const long long total = NX4 + NREST;
    for (long long u = (long long)blockIdx.x * 256 + threadIdx.x; u < total;
         u += (long long)gridDim.x * 256) {
        if (u < NX4) {
            float4 v = ((const float4*)x)[u];
            short4v o;
            o[0] = (short)f2b(v.x); o[1] = (short)f2b(v.y);
            o[2] = (short)f2b(v.z); o[3] = (short)f2b(v.w);
            *(short4v*)&x_bf[u * 4] = o;
        } else {
            long long i = u - NX4;
            if (i < 1048576) { Wih_bf[i] = f2b(Wih[i]); continue; }
            i -= 1048576;
            if (i < 1048576) { Whh_bf[i] = f2b(Whh[i]); continue; }
            i -= 1048576;
            if (i < 524288) {
                int row = (int)(i >> 10), col = (int)(i & 1023);
                if (col < 512) U1a[row * 512 + col] = f2b(U1[i]);
                else           U1b[row * 512 + (col - 512)] = f2b(U1[i]);
                continue;
            }
            i -= 524288;
            if (i < 262144) { U2b[i] = f2b(U2[i]); continue; }
            i -= 262144;
            bias[i] = bih[i] + bhh[i];
        }
    }
}

// ---------------------------------------------------------------------------
// gemm_bt: C[m][n] = sum_k A[m][k]*B[n][k] (+bias[n]); bf16 in/out, fp32 acc.
// 128x128 block tile, BK=64, 4 waves of 64x64.
// mode==1: scatter-store into xg layout [t][jg][b][c], c = gate*16 + (n&15),
//          jg = (n>>4)&31, gate = n>>9  (tile rows = 128 consecutive t, one b)
// ---------------------------------------------------------------------------
__global__ __launch_bounds__(256) void gemm_bt(
    const unsigned short* __restrict__ A, long long lda,
    const unsigned short* __restrict__ Bm, long long ldb,
    unsigned short* __restrict__ C, long long ldc,
    const float* __restrict__ bias, int mode)
{
    __shared__ __align__(16) unsigned short sbuf[2 * 128 * 72];
    unsigned short* At = sbuf;
    unsigned short* Bt = sbuf + 128 * 72;
    unsigned short* Ct = sbuf;  // alias, used after final sync

    const int m0 = blockIdx.x * 128, n0 = blockIdx.y * 128;
    const int tid = threadIdx.x;
    const int wv = tid >> 6, lane = tid & 63, l15 = lane & 15, q = lane >> 4;
    const int wm = wv & 1, wn = wv >> 1;

    floatx4 acc[4][4];
    for (int i = 0; i < 4; i++)
        for (int j = 0; j < 4; j++) acc[i][j] = (floatx4){0.f, 0.f, 0.f, 0.f};

    for (int k0 = 0; k0 < 512; k0 += 64) {
        for (int p = 0; p < 4; p++) {
            int idx = tid + p * 256;
            int row = idx >> 3, ch = idx & 7;
            *(short8*)&At[row * 72 + ch * 8] =
                *(const short8*)&A[(long long)(m0 + row) * lda + k0 + ch * 8];
            *(short8*)&Bt[row * 72 + ch * 8] =
                *(const short8*)&Bm[(long long)(n0 + row) * ldb + k0 + ch * 8];
        }
        __syncthreads();
        for (int ks = 0; ks < 64; ks += 32) {
            short8 af[4], bfv[4];
            for (int mi = 0; mi < 4; mi++)
                af[mi] = *(const short8*)&At[(wm * 64 + mi * 16 + l15) * 72 + ks + q * 8];
            for (int ni = 0; ni < 4; ni++)
                bfv[ni] = *(const short8*)&Bt[(wn * 64 + ni * 16 + l15) * 72 + ks + q * 8];
            for (int mi = 0; mi < 4; mi++)
                for (int ni = 0; ni < 4; ni++)
                    acc[mi][ni] = MFMA16(af[mi], bfv[ni], acc[mi][ni]);
        }
        __syncthreads();
    }

    float bv[4];
    for (int ni = 0; ni < 4; ni++)
        bv[ni] = bias ? bias[n0 + wn * 64 + ni * 16 + l15] : 0.0f;

    for (int mi = 0; mi < 4; mi++)
        for (int ni = 0; ni < 4; ni++)
            for (int r = 0; r < 4; r++)
                Ct[(wm * 64 + mi * 16 + q * 4 + r) * 128 + wn * 64 + ni * 16 + l15] =
                    f2b(acc[mi][ni][r] + bv[ni]);
    __syncthreads();

    const int tt0 = m0 & 511, bglob = m0 >> 9;
    for (int p = 0; p < 8; p++) {
        int idx = tid + p * 256;
        int row = idx >> 4, ch = idx & 15;
        if (mode) {
            int n = n0 + ch * 8;
            int gate = n >> 9, jg = (n >> 4) & 31, c0 = gate * 16 + (n & 15);
            long long dst = (((long long)(tt0 + row) * 32 + jg) * 128 + bglob) * 64 + c0;
            *(short8*)&C[dst] = *(const short8*)&Ct[row * 128 + ch * 8];
        } else {
            *(short8*)&C[(long long)(m0 + row) * ldc + n0 + ch * 8] =
                *(const short8*)&Ct[row * 128 + ch * 8];
        }
    }
}

// ---------------------------------------------------------------------------
// lstm_rec: 64 WGs = 8 bg x 8 hid-groups (jgb). Wave wv owns hid =
// jgb*64 + wv*16 + l15 for ALL FOUR GATES (Wreg[ct][kk], VGPR/AGPR-resident).
// Ring layout (same as R7): word w = b_local*512 + hid in slab [slot][bg],
// value = (t<<16)|bf16. NEW: consumer lane tid bulk-reads its contiguous
// 128B (words tid*32..+31) via ONE asm burst of 8 dwordx4 sc0 sc1 loads +
// single vmcnt(0) — pipelined, ~1 IC RTT. Tag check; rare retries use 8B
// atomic loads (guaranteed-coherent fallback).
// ---------------------------------------------------------------------------
__global__ __launch_bounds__(256, 1) void lstm_rec(
    const unsigned short* __restrict__ xg,   // [t][jg32][b][c]  c = gate*16+hl
    const unsigned short* __restrict__ Whh,  // (2048, 512) bf16
    unsigned short* __restrict__ h_all,      // [b][t][h]  (128, 512, 512)
    unsigned int* __restrict__ ring)         // [2][8][8192] tagged words
{
    __shared__ unsigned int At[2][16 * 264];  // 16 batches x 256 pair-words

    const int tid = threadIdx.x;
    const int wv = tid >> 6, lane = tid & 63, l15 = lane & 15, q = lane >> 4;
    const int bg = blockIdx.x >> 3, jgb = blockIdx.x & 7;
    const int b0 = bg * 16;
    const int jg32 = jgb * 4 + wv;            // 16-hid group of this wave
    const int hid = jg32 * 16 + l15;          // this lane's hidden index

    // W_hh B-frags: Wreg[ct][kk], row = ct*512 + hid, k = kk*32 + q*8
    short8 Wreg[4][16];
    #pragma unroll
    for (int ct = 0; ct < 4; ct++)
        #pragma unroll
        for (int kk = 0; kk < 16; kk++)
            Wreg[ct][kk] = *(const short8*)
                &Whh[(long long)(ct * 512 + hid) * 512 + kk * 32 + q * 8];

    float cst[4] = {0.f, 0.f, 0.f, 0.f};

    for (int t = 0; t < 512; t++) {
        // ---- xg prefetch (issued first; HBM latency overlaps the poll) ----
        const long long xbase = ((long long)(t * 32 + jg32) * 128 + b0) * 64;
        floatx4 acc[4];
        #pragma unroll
        for (int ct = 0; ct < 4; ct++)
            #pragma unroll
            for (int r = 0; r < 4; r++)
                acc[ct][r] = b2f(xg[xbase + (q * 4 + r) * 64 + ct * 16 + l15]);

        if (t > 0) {
            const unsigned want = (unsigned)(t - 1);
            const int sl = (t - 1) & 1;
            const unsigned int* slab = ring + sl * 65536 + bg * 8192;
            unsigned long long a64 = (unsigned long long)slab
                                   + (unsigned long long)tid * 128ull;
            // ---- ONE pipelined burst: 8 x 16B coherent loads, one drain ----
            uintx4 d0, d1, d2, d3, d4, d5, d6, d7;
            asm volatile(
                "global_load_dwordx4 %0, %8, off sc0 sc1\n\t"
                "global_load_dwordx4 %1, %8, off offset:16 sc0 sc1\n\t"
                "global_load_dwordx4 %2, %8, off offset:32 sc0 sc1\n\t"
                "global_load_dwordx4 %3, %8, off offset:48 sc0 sc1\n\t"
                "global_load_dwordx4 %4, %8, off offset:64 sc0 sc1\n\t"
                "global_load_dwordx4 %5, %8, off offset:80 sc0 sc1\n\t"
                "global_load_dwordx4 %6, %8, off offset:96 sc0 sc1\n\t"
                "global_load_dwordx4 %7, %8, off offset:112 sc0 sc1\n\t"
                "s_waitcnt vmcnt(0)"
                : "=&v"(d0), "=&v"(d1), "=&v"(d2), "=&v"(d3),
                  "=&v"(d4), "=&v"(d5), "=&v"(d6), "=&v"(d7)
                : "v"(a64)
                : "memory");
            unsigned w[32];
            #pragma unroll
            for (int j = 0; j < 4; j++) {
                w[0 + j]  = d0[j]; w[4 + j]  = d1[j];
                w[8 + j]  = d2[j]; w[12 + j] = d3[j];
                w[16 + j] = d4[j]; w[20 + j] = d5[j];
                w[24 + j] = d6[j]; w[28 + j] = d7[j];
            }
            // tag check; retries via guaranteed-coherent 8B atomic loads
            unsigned bad = 0;
            #pragma unroll
            for (int i = 0; i < 32; i++) bad |= (w[i] >> 16) ^ want;
            if (bad) {
                const unsigned long long* slab64 =
                    (const unsigned long long*)slab;
                while (true) {
                    unsigned b2 = 0;
                    #pragma unroll
                    for (int i = 0; i < 16; i++) {
                        if (((w[2 * i] >> 16) ^ want) |
                            ((w[2 * i + 1] >> 16) ^ want)) {
                            unsigned long long v = __hip_atomic_load(
                                &slab64[tid * 16 + i], __ATOMIC_RELAXED,
                                __HIP_MEMORY_SCOPE_AGENT);
                            w[2 * i] = (unsigned)v;
                            w[2 * i + 1] = (unsigned)(v >> 32);
                        }
                        b2 |= ((w[2 * i] >> 16) ^ want) |
                              ((w[2 * i + 1] >> 16) ^ want);
                    }
                    if (!b2) break;
                }
            }
            // ---- LDS stage: lane's 32 words are contiguous (row tid>>4) ----
            unsigned int* dst = &At[sl][(tid >> 4) * 264 + (tid & 15) * 16];
            #pragma unroll
            for (int j = 0; j < 16; j++)
                dst[j] = (w[2 * j] & 0xFFFFu) | (w[2 * j + 1] << 16);
            __syncthreads();
            // MFMA: A = h tile (batch l15, K), B = Wreg; 4 chains (one/gate)
            const unsigned int* ap = &At[sl][l15 * 264 + q * 4];
            #pragma unroll
            for (int kk = 0; kk < 16; kk++) {
                short8 af = *(const short8*)(ap + kk * 16);
                acc[0] = MFMA16(af, Wreg[0][kk], acc[0]);
                acc[1] = MFMA16(af, Wreg[1][kk], acc[1]);
                acc[2] = MFMA16(af, Wreg[2][kk], acc[2]);
                acc[3] = MFMA16(af, Wreg[3][kk], acc[3]);
            }
        }
        // ---- pointwise: gates in-lane (acc[0..3] = i,f,g,o) ----
        unsigned short hbv[4];
        #pragma unroll
        for (int r = 0; r < 4; r++) {
            float ig = sigm(acc[0][r]);
            float fg = sigm(acc[1][r]);
            float gv = tanh_(acc[2][r]);
            float og = sigm(acc[3][r]);
            cst[r] = fg * cst[r] + ig * gv;
            hbv[r] = f2b(og * tanh_(cst[r]));
        }
        // publish: ring first (latency-critical), then h_all
        #pragma unroll
        for (int r = 0; r < 4; r++) {
            __hip_atomic_store(
                &ring[(t & 1) * 65536 + bg * 8192 + (q * 4 + r) * 512 + hid],
                ((unsigned)t << 16) | hbv[r], __ATOMIC_RELAXED,
                __HIP_MEMORY_SCOPE_AGENT);
        }
        #pragma unroll
        for (int r = 0; r < 4; r++) {
            const int b = b0 + q * 4 + r;
            h_all[(long long)b * 262144 + (long long)t * 512 + hid] = hbv[r];
        }
    }
}

// ---------------------------------------------------------------------------
// attn_e: e[b,t] = Ve . tanh(h@U1a^T + u1b[b] + x@U2^T), fused, 32 t per WG.
// ---------------------------------------------------------------------------
__global__ __launch_bounds__(256) void attn_e(
    const unsigned short* __restrict__ h_all,
    const unsigned short* __restrict__ x_bf,
    const unsigned short* __restrict__ U1a, const unsigned short* __restrict__ U2b,
    const unsigned short* __restrict__ u1b,  // bf16 (128,512)
    const float* __restrict__ Ve,
    float* __restrict__ e)
{
    __shared__ __align__(16) unsigned short Bt[512 * 40];
    __shared__ __align__(16) unsigned short At[32 * 40];
    __shared__ float ered[4][32];

    const int tid = threadIdx.x;
    const int wv = tid >> 6, lane = tid & 63, l15 = lane & 15, q = lane >> 4;
    const int b = blockIdx.x >> 4, t0 = (blockIdx.x & 15) * 32;

    floatx4 acc[2][8];
    for (int mi = 0; mi < 2; mi++)
        for (int ni = 0; ni < 8; ni++) acc[mi][ni] = (floatx4){0.f, 0.f, 0.f, 0.f};

    for (int it = 0; it < 32; it++) {
        const int phase = it >> 4, kk = (it & 15) * 32;
        const unsigned short* Asrc = phase ? x_bf : h_all;
        const unsigned short* Bsrc = phase ? U2b : U1a;
        __syncthreads();
        for (int idx = tid; idx < 2048; idx += 256) {
            int row = idx >> 2, ch = idx & 3;
            *(short8*)&Bt[row * 40 + ch * 8] =
                *(const short8*)&Bsrc[(long long)row * 512 + kk + ch * 8];
        }
        if (tid < 128) {
            int row = tid >> 2, ch = tid & 3;
            *(short8*)&At[row * 40 + ch * 8] =
                *(const short8*)&Asrc[(long long)(b * 512 + t0 + row) * 512 + kk + ch * 8];
        }
        __syncthreads();
        short8 af[2];
        for (int mi = 0; mi < 2; mi++)
            af[mi] = *(const short8*)&At[(mi * 16 + l15) * 40 + q * 8];
        for (int ni = 0; ni < 8; ni++) {
            short8 bfv = *(const short8*)&Bt[(wv * 128 + ni * 16 + l15) * 40 + q * 8];
            acc[0][ni] = MFMA16(af[0], bfv, acc[0][ni]);
            acc[1][ni] = MFMA16(af[1], bfv, acc[1][ni]);
        }
    }

    float s[2][4] = {{0.f, 0.f, 0.f, 0.f}, {0.f, 0.f, 0.f, 0.f}};
    for (int ni = 0; ni < 8; ni++) {
        int n = wv * 128 + ni * 16 + l15;
        float ub = b2f(u1b[b * 512 + n]);
        float vev = Ve[n];
        for (int mi = 0; mi < 2; mi++)
            for (int r = 0; r < 4; r++)
                s[mi][r] += vev * tanh_(acc[mi][ni][r] + ub);
    }
    for (int off = 1; off <= 8; off <<= 1)
        for (int mi = 0; mi < 2; mi++)
            for (int r = 0; r < 4; r++) s[mi][r] += __shfl_xor(s[mi][r], off);
    if (l15 == 0)
        for (int mi = 0; mi < 2; mi++)
            for (int r = 0; r < 4; r++) ered[wv][mi * 16 + q * 4 + r] = s[mi][r];
    __syncthreads();
    if (tid < 32)
        e[(long long)b * 512 + t0 + tid] =
            ered[0][tid] + ered[1][tid] + ered[2][tid] + ered[3][tid];
}

// ---------------------------------------------------------------------------
// attn_out: softmax over T, context = alpha.h, head -> mu, sigma. 1 WG per b.
// ---------------------------------------------------------------------------
__global__ __launch_bounds__(256) void attn_out(
    const float* __restrict__ e, const unsigned short* __restrict__ h_all,
    const float* __restrict__ Wout, const float* __restrict__ bout,
    float* __restrict__ outp)
{
    __shared__ float sm[512];
    __shared__ float red[8];
    const int b = blockIdx.x, tid = threadIdx.x;
    const int wv = tid >> 6, lane = tid & 63;

    float e0 = e[b * 512 + tid], e1 = e[b * 512 + 256 + tid];
    float mx = fmaxf(e0, e1);
    for (int off = 32; off; off >>= 1) mx = fmaxf(mx, __shfl_xor(mx, off));
    if (lane == 0) red[wv] = mx;
    __syncthreads();
    mx = fmaxf(fmaxf(red[0], red[1]), fmaxf(red[2], red[3]));

    float s0 = __expf(e0 - mx), s1 = __expf(e1 - mx);
    sm[tid] = s0; sm[256 + tid] = s1;
    float ss = s0 + s1;
    for (int off = 32; off; off >>= 1) ss += __shfl_xor(ss, off);
    if (lane == 0) red[4 + wv] = ss;
    __syncthreads();
    float inv = 1.0f / (red[4] + red[5] + red[6] + red[7]);

    const long long base = (long long)b * 262144;
    float a0 = 0.f, a1 = 0.f;
    for (int t = 0; t < 512; t++) {
        float al = sm[t];
        a0 += al * b2f(h_all[base + t * 512 + tid]);
        a1 += al * b2f(h_all[base + t * 512 + 256 + tid]);
    }
    a0 *= inv; a1 *= inv;

    float q0 = a0 * Wout[tid] + a1 * Wout[256 + tid];
    float q1 = a0 * Wout[512 + tid] + a1 * Wout[768 + tid];
    for (int off = 32; off; off >>= 1) { q0 += __shfl_xor(q0, off); q1 += __shfl_xor(q1, off); }
    __syncthreads();  // red reuse
    if (lane == 0) { red[wv] = q0; red[4 + wv] = q1; }
    __syncthreads();
    if (tid == 0) {
        float P0 = red[0] + red[1] + red[2] + red[3] + bout[0];
        float P1 = red[4] + red[5] + red[6] + red[7] + bout[1];
        outp[b] = P0;
        float sp = (P1 > 15.0f) ? P1 : log1pf(__expf(P1));
        outp[128 + b] = sp + 1e-5f;
    }
}

// ---------------------------------------------------------------------------
extern "C" void kernel_launch(void* const* d_in, const int* in_sizes, int n_in,
                              void* d_out, int out_size, void* d_ws, size_t ws_size,
                              hipStream_t stream)
{
    const float* x    = (const float*)d_in[0];
    const float* Wih  = (const float*)d_in[1];
    const float* Whh  = (const float*)d_in[2];
    const float* bih  = (const float*)d_in[3];
    const float* bhh  = (const float*)d_in[4];
    const float* Ve   = (const float*)d_in[5];
    const float* U1   = (const float*)d_in[6];
    const float* U2   = (const float*)d_in[7];
    const float* Wout = (const float*)d_in[8];
    const float* bout = (const float*)d_in[9];
    float* out = (float*)d_out;

    char* ws = (char*)d_ws;
    size_t off = 0;
    auto alloc = [&](size_t bytes) -> void* {
        void* p = ws + off;
        off += (bytes + 255) & ~(size_t)255;
        return p;
    };
    unsigned short* x_bf   = (unsigned short*)alloc(33554432ull * 2);
    unsigned short* Wih_bf = (unsigned short*)alloc(1048576ull * 2);
    unsigned short* Whh_bf = (unsigned short*)alloc(1048576ull * 2);
    unsigned short* U1a    = (unsigned short*)alloc(262144ull * 2);
    unsigned short* U1b    = (unsigned short*)alloc(262144ull * 2);
    unsigned short* U2b    = (unsigned short*)alloc(262144ull * 2);
    float*          bias   = (float*)alloc(2048ull * 4);
    unsigned short* xg     = (unsigned short*)alloc(134217728ull * 2);
    unsigned short* h_all  = (unsigned short*)alloc(33554432ull * 2);
    unsigned short* u1bv   = (unsigned short*)alloc(65536ull * 2);
    float*          e      = (float*)alloc(65536ull * 4);
    unsigned int*   ring   = (unsigned int*)alloc(131072ull * 4);  // 2x8x8192 tagged
    if (off > ws_size) return;  // workspace too small: fail safe (no corruption)

    prep<<<4096, 256, 0, stream>>>(x, Wih, Whh, bih, bhh, U1, U2,
                                   x_bf, Wih_bf, Whh_bf, U1a, U1b, U2b, bias);
    // xg = x @ W_ih^T + b, scattered into [t][jg][b][c]
    gemm_bt<<<dim3(512, 16), 256, 0, stream>>>(x_bf, 512, Wih_bf, 512,
                                               xg, 2048, bias, 1);
    lstm_rec<<<64, 256, 0, stream>>>(xg, Whh_bf, h_all, ring);
    // u1b = h_last @ U1b^T
    gemm_bt<<<dim3(1, 4), 256, 0, stream>>>(h_all + 511 * 512, 262144, U1b, 512,
                                            u1bv, 512, nullptr, 0);
    attn_e<<<2048, 256, 0, stream>>>(h_all, x_bf, U1a, U2b, u1bv, Ve, e);
    attn_out<<<128, 256, 0, stream>>>(e, h_all, Wout, bout, out);
}

// Round 10
// 2752.382 us; speedup vs baseline: 1.5736x; 1.3683x over previous
//
#include <hip/hip_runtime.h>
#include <stdint.h>

// ---------------------------------------------------------------------------
// MarketScoringUnit: LSTM(B=128,T=512,H=512) + attention + (mu, sigma) head.
// Round 10: lstm_rec reverted to R7 exactly (proven 1911us floor for the
// exchange design). New: 3/4 of the xg GEMM overlapped with the recurrence
// via a mega-kernel (64 lstm WGs + 6144 gemm WGs, one release/acquire
// done-counter guard at t==128). attn_out h-loads packed.
// ---------------------------------------------------------------------------

using short8  = __attribute__((ext_vector_type(8))) short;   // 8 bf16 (4 VGPRs)
using short4v = __attribute__((ext_vector_type(4))) short;
using floatx4 = __attribute__((ext_vector_type(4))) float;

#define MFMA16(a, b, c) __builtin_amdgcn_mfma_f32_16x16x32_bf16((a), (b), (c), 0, 0, 0)

__device__ __forceinline__ unsigned short f2b(float f) {
    unsigned u = __float_as_uint(f);
    u += 0x7FFFu + ((u >> 16) & 1u);           // RNE
    return (unsigned short)(u >> 16);
}
__device__ __forceinline__ float b2f(unsigned short h) {
    return __uint_as_float(((unsigned)h) << 16);
}
__device__ __forceinline__ float sigm(float x) { return 1.0f / (1.0f + __expf(-x)); }
__device__ __forceinline__ float tanh_(float x) { return 1.0f - 2.0f / (__expf(2.0f * x) + 1.0f); }

// ---------------------------------------------------------------------------
// prep: fp32 -> bf16 conversions, U1 split into U1a/U1b, bias = b_ih + b_hh
// ---------------------------------------------------------------------------
__global__ __launch_bounds__(256) void prep(
    const float* __restrict__ x, const float* __restrict__ Wih, const float* __restrict__ Whh,
    const float* __restrict__ bih, const float* __restrict__ bhh,
    const float* __restrict__ U1, const float* __restrict__ U2,
    unsigned short* __restrict__ x_bf, unsigned short* __restrict__ Wih_bf,
    unsigned short* __restrict__ Whh_bf, unsigned short* __restrict__ U1a,
    unsigned short* __restrict__ U1b, unsigned short* __restrict__ U2b,
    float* __restrict__ bias)
{
    const long long NX4 = 33554432LL / 4;  // x as float4
    const long long NREST = 1048576LL + 1048576LL + 524288LL + 262144LL + 2048LL;
    const long long total = NX4 + NREST;
    for (long long u = (long long)blockIdx.x * 256 + threadIdx.x; u < total;
         u += (long long)gridDim.x * 256) {
        if (u < NX4) {
            float4 v = ((const float4*)x)[u];
            short4v o;
            o[0] = (short)f2b(v.x); o[1] = (short)f2b(v.y);
            o[2] = (short)f2b(v.z); o[3] = (short)f2b(v.w);
            *(short4v*)&x_bf[u * 4] = o;
        } else {
            long long i = u - NX4;
            if (i < 1048576) { Wih_bf[i] = f2b(Wih[i]); continue; }
            i -= 1048576;
            if (i < 1048576) { Whh_bf[i] = f2b(Whh[i]); continue; }
            i -= 1048576;
            if (i < 524288) {
                int row = (int)(i >> 10), col = (int)(i & 1023);
                if (col < 512) U1a[row * 512 + col] = f2b(U1[i]);
                else           U1b[row * 512 + (col - 512)] = f2b(U1[i]);
                continue;
            }
            i -= 524288;
            if (i < 262144) { U2b[i] = f2b(U2[i]); continue; }
            i -= 262144;
            bias[i] = bih[i] + bhh[i];
        }
    }
}

// ---------------------------------------------------------------------------
// gemm_core: C[m][n] = sum_k A[m][k]*B[n][k] (+bias[n]); bf16, fp32 acc.
// 128x128 tile, BK=64, 4 waves of 64x64. mode==1: scatter into xg layout
// [t][jg][b][c], c = gate*16+(n&15), jg=(n>>4)&31, gate=n>>9.
// ---------------------------------------------------------------------------
__device__ __forceinline__ void gemm_core(
    const unsigned short* __restrict__ A, long long lda,
    const unsigned short* __restrict__ Bm, long long ldb,
    unsigned short* __restrict__ C, long long ldc,
    const float* __restrict__ bias, int mode,
    int m0, int n0, int tid, unsigned short* sbuf)
{
    unsigned short* At = sbuf;
    unsigned short* Bt = sbuf + 128 * 72;
    unsigned short* Ct = sbuf;  // alias, used after final sync

    const int wv = tid >> 6, lane = tid & 63, l15 = lane & 15, q = lane >> 4;
    const int wm = wv & 1, wn = wv >> 1;

    floatx4 acc[4][4];
    for (int i = 0; i < 4; i++)
        for (int j = 0; j < 4; j++) acc[i][j] = (floatx4){0.f, 0.f, 0.f, 0.f};

    for (int k0 = 0; k0 < 512; k0 += 64) {
        for (int p = 0; p < 4; p++) {
            int idx = tid + p * 256;
            int row = idx >> 3, ch = idx & 7;
            *(short8*)&At[row * 72 + ch * 8] =
                *(const short8*)&A[(long long)(m0 + row) * lda + k0 + ch * 8];
            *(short8*)&Bt[row * 72 + ch * 8] =
                *(const short8*)&Bm[(long long)(n0 + row) * ldb + k0 + ch * 8];
        }
        __syncthreads();
        for (int ks = 0; ks < 64; ks += 32) {
            short8 af[4], bfv[4];
            for (int mi = 0; mi < 4; mi++)
                af[mi] = *(const short8*)&At[(wm * 64 + mi * 16 + l15) * 72 + ks + q * 8];
            for (int ni = 0; ni < 4; ni++)
                bfv[ni] = *(const short8*)&Bt[(wn * 64 + ni * 16 + l15) * 72 + ks + q * 8];
            for (int mi = 0; mi < 4; mi++)
                for (int ni = 0; ni < 4; ni++)
                    acc[mi][ni] = MFMA16(af[mi], bfv[ni], acc[mi][ni]);
        }
        __syncthreads();
    }

    float bv[4];
    for (int ni = 0; ni < 4; ni++)
        bv[ni] = bias ? bias[n0 + wn * 64 + ni * 16 + l15] : 0.0f;

    for (int mi = 0; mi < 4; mi++)
        for (int ni = 0; ni < 4; ni++)
            for (int r = 0; r < 4; r++)
                Ct[(wm * 64 + mi * 16 + q * 4 + r) * 128 + wn * 64 + ni * 16 + l15] =
                    f2b(acc[mi][ni][r] + bv[ni]);
    __syncthreads();

    const int tt0 = m0 & 511, bglob = m0 >> 9;
    for (int p = 0; p < 8; p++) {
        int idx = tid + p * 256;
        int row = idx >> 4, ch = idx & 15;
        if (mode) {
            int n = n0 + ch * 8;
            int gate = n >> 9, jg = (n >> 4) & 31, c0 = gate * 16 + (n & 15);
            long long dst = (((long long)(tt0 + row) * 32 + jg) * 128 + bglob) * 64 + c0;
            *(short8*)&C[dst] = *(const short8*)&Ct[row * 128 + ch * 8];
        } else {
            *(short8*)&C[(long long)(m0 + row) * ldc + n0 + ch * 8] =
                *(const short8*)&Ct[row * 128 + ch * 8];
        }
    }
}

__global__ __launch_bounds__(256) void gemm_bt(
    const unsigned short* __restrict__ A, long long lda,
    const unsigned short* __restrict__ Bm, long long ldb,
    unsigned short* __restrict__ C, long long ldc,
    const float* __restrict__ bias, int mode, int mmul)
{
    __shared__ __align__(16) unsigned short sbuf[2 * 128 * 72];
    gemm_core(A, lda, Bm, ldb, C, ldc, bias, mode,
              blockIdx.x * mmul, blockIdx.y * 128, threadIdx.x, sbuf);
}

// ---------------------------------------------------------------------------
// mega: blockIdx < 64 -> lstm recurrence (R7 verbatim + done-guard at t==128)
//       blockIdx >= 64 -> xg GEMM for t in [128, 512)  (6144 WGs)
// lstm WGs are blockIdx 0..63 (dispatched first -> co-resident); gemm WGs
// never wait on anything, so they always drain: no deadlock. The guard is a
// one-time release/acquire counter handoff (standard HIP pattern).
// ---------------------------------------------------------------------------
#define GEMM_WGS 6144
__global__ __launch_bounds__(256, 1) void mega(
    const unsigned short* __restrict__ xg,   // [t][jg32][b][c]  c = gate*16+hl
    const unsigned short* __restrict__ Whh,  // (2048, 512) bf16
    unsigned short* __restrict__ h_all,      // [b][t][h]  (128, 512, 512)
    unsigned int* __restrict__ ring,         // [2][128][512] tagged words
    const unsigned short* __restrict__ x_bf,
    const unsigned short* __restrict__ Wih_bf,
    const float* __restrict__ bias,
    unsigned short* __restrict__ xg_out,
    int* __restrict__ done)
{
    __shared__ __align__(16) char smem[36864];

    const int tid = threadIdx.x;

    if (blockIdx.x >= 64) {
        // ---------------- xg GEMM role: t in [128,512) ----------------
        int g = blockIdx.x - 64;
        int b = g & 127;
        int r = g >> 7;                  // 0..47
        int ti = 1 + (r % 3);            // 1..3
        int n = r / 3;                   // 0..15
        gemm_core(x_bf, 512, Wih_bf, 512, xg_out, 2048, bias, 1,
                  b * 512 + ti * 128, n * 128, tid, (unsigned short*)smem);
        __syncthreads();                 // all waves' stores drained
        if (tid == 0)
            __hip_atomic_fetch_add(done, 1, __ATOMIC_RELEASE,
                                   __HIP_MEMORY_SCOPE_AGENT);
        return;
    }

    // ---------------- lstm role (R7 verbatim) ----------------
    unsigned int (*At)[16 * 264] = (unsigned int (*)[16 * 264])smem;

    const int wv = tid >> 6, lane = tid & 63, l15 = lane & 15, q = lane >> 4;
    const int bg = blockIdx.x >> 3, jgb = blockIdx.x & 7;
    const int b0 = bg * 16;
    const int jg32 = jgb * 4 + wv;            // 16-hid group of this wave
    const int hid = jg32 * 16 + l15;          // this lane's hidden index

    // W_hh B-frags: Wreg[ct][kk], row = ct*512 + hid, k = kk*32 + q*8
    short8 Wreg[4][16];
    #pragma unroll
    for (int ct = 0; ct < 4; ct++)
        #pragma unroll
        for (int kk = 0; kk < 16; kk++)
            Wreg[ct][kk] = *(const short8*)
                &Whh[(long long)(ct * 512 + hid) * 512 + kk * 32 + q * 8];

    float cst[4] = {0.f, 0.f, 0.f, 0.f};

    for (int t = 0; t < 512; t++) {
        // one-time guard: xg[t>=128] is produced by the gemm role
        if (t == 128) {
            if (tid == 0) {
                while (__hip_atomic_load(done, __ATOMIC_ACQUIRE,
                                         __HIP_MEMORY_SCOPE_AGENT) < GEMM_WGS)
                    __builtin_amdgcn_s_sleep(8);
            }
            __syncthreads();
        }
        // ---- prefetch xg: acc-init values, 16 scalar loads (pre-poll) ----
        const long long xbase = ((long long)(t * 32 + jg32) * 128 + b0) * 64;
        floatx4 acc[4];
        #pragma unroll
        for (int ct = 0; ct < 4; ct++)
            #pragma unroll
            for (int r = 0; r < 4; r++)
                acc[ct][r] = b2f(xg[xbase + (q * 4 + r) * 64 + ct * 16 + l15]);

        if (t > 0) {
            const unsigned want = (unsigned)(t - 1);
            const int sl = (t - 1) & 1;
            unsigned long long* rb = (unsigned long long*)
                (ring + sl * 65536 + b0 * 512);
            unsigned long long w[16];
            #pragma unroll
            for (int i = 0; i < 16; i++)
                w[i] = __hip_atomic_load(&rb[tid + i * 256], __ATOMIC_RELAXED,
                                         __HIP_MEMORY_SCOPE_AGENT);
            while (true) {
                unsigned bad = 0;
                #pragma unroll
                for (int i = 0; i < 16; i++) {
                    unsigned lo = (unsigned)(w[i] >> 16) & 0xFFFFu;
                    unsigned hi = (unsigned)(w[i] >> 48);
                    bad |= (lo ^ want) | (hi ^ want);
                }
                if (!bad) break;
                #pragma unroll
                for (int i = 0; i < 16; i++) {
                    unsigned lo = (unsigned)(w[i] >> 16) & 0xFFFFu;
                    unsigned hi = (unsigned)(w[i] >> 48);
                    if ((lo ^ want) | (hi ^ want))
                        w[i] = __hip_atomic_load(&rb[tid + i * 256], __ATOMIC_RELAXED,
                                                 __HIP_MEMORY_SCOPE_AGENT);
                }
            }
            // strip tags, pack two bf16 per LDS word
            unsigned int* dst = &At[sl][0];
            #pragma unroll
            for (int i = 0; i < 16; i++) {
                int idx = tid + i * 256;
                int row = idx >> 8, k = idx & 255;
                dst[row * 264 + k] =
                    (unsigned)(w[i] & 0xFFFFu) | ((unsigned)(w[i] >> 32) << 16);
            }
            __syncthreads();
            // MFMA: A = h tile (batch l15, K), B = Wreg; 4 chains (one/gate)
            const unsigned int* ap = &At[sl][l15 * 264 + q * 4];
            #pragma unroll
            for (int kk = 0; kk < 16; kk++) {
                short8 af = *(const short8*)(ap + kk * 16);
                acc[0] = MFMA16(af, Wreg[0][kk], acc[0]);
                acc[1] = MFMA16(af, Wreg[1][kk], acc[1]);
                acc[2] = MFMA16(af, Wreg[2][kk], acc[2]);
                acc[3] = MFMA16(af, Wreg[3][kk], acc[3]);
            }
        }
        // ---- pointwise: gates are in-lane (acc[0..3] = i,f,g,o) ----
        unsigned short hbv[4];
        #pragma unroll
        for (int r = 0; r < 4; r++) {
            float ig = sigm(acc[0][r]);
            float fg = sigm(acc[1][r]);
            float gv = tanh_(acc[2][r]);
            float og = sigm(acc[3][r]);
            cst[r] = fg * cst[r] + ig * gv;
            hbv[r] = f2b(og * tanh_(cst[r]));
        }
        // publish: ring first (latency-critical), then h_all
        #pragma unroll
        for (int r = 0; r < 4; r++) {
            const int b = b0 + q * 4 + r;
            __hip_atomic_store(&ring[(t & 1) * 65536 + b * 512 + hid],
                               ((unsigned)t << 16) | hbv[r], __ATOMIC_RELAXED,
                               __HIP_MEMORY_SCOPE_AGENT);
        }
        #pragma unroll
        for (int r = 0; r < 4; r++) {
            const int b = b0 + q * 4 + r;
            h_all[(long long)b * 262144 + (long long)t * 512 + hid] = hbv[r];
        }
    }
}

// ---------------------------------------------------------------------------
// attn_e: e[b,t] = Ve . tanh(h@U1a^T + u1b[b] + x@U2^T), fused, 32 t per WG.
// ---------------------------------------------------------------------------
__global__ __launch_bounds__(256) void attn_e(
    const unsigned short* __restrict__ h_all,
    const unsigned short* __restrict__ x_bf,
    const unsigned short* __restrict__ U1a, const unsigned short* __restrict__ U2b,
    const unsigned short* __restrict__ u1b,  // bf16 (128,512)
    const float* __restrict__ Ve,
    float* __restrict__ e)
{
    __shared__ __align__(16) unsigned short Bt[512 * 40];
    __shared__ __align__(16) unsigned short At[32 * 40];
    __shared__ float ered[4][32];

    const int tid = threadIdx.x;
    const int wv = tid >> 6, lane = tid & 63, l15 = lane & 15, q = lane >> 4;
    const int b = blockIdx.x >> 4, t0 = (blockIdx.x & 15) * 32;

    floatx4 acc[2][8];
    for (int mi = 0; mi < 2; mi++)
        for (int ni = 0; ni < 8; ni++) acc[mi][ni] = (floatx4){0.f, 0.f, 0.f, 0.f};

    for (int it = 0; it < 32; it++) {
        const int phase = it >> 4, kk = (it & 15) * 32;
        const unsigned short* Asrc = phase ? x_bf : h_all;
        const unsigned short* Bsrc = phase ? U2b : U1a;
        __syncthreads();
        for (int idx = tid; idx < 2048; idx += 256) {
            int row = idx >> 2, ch = idx & 3;
            *(short8*)&Bt[row * 40 + ch * 8] =
                *(const short8*)&Bsrc[(long long)row * 512 + kk + ch * 8];
        }
        if (tid < 128) {
            int row = tid >> 2, ch = tid & 3;
            *(short8*)&At[row * 40 + ch * 8] =
                *(const short8*)&Asrc[(long long)(b * 512 + t0 + row) * 512 + kk + ch * 8];
        }
        __syncthreads();
        short8 af[2];
        for (int mi = 0; mi < 2; mi++)
            af[mi] = *(const short8*)&At[(mi * 16 + l15) * 40 + q * 8];
        for (int ni = 0; ni < 8; ni++) {
            short8 bfv = *(const short8*)&Bt[(wv * 128 + ni * 16 + l15) * 40 + q * 8];
            acc[0][ni] = MFMA16(af[0], bfv, acc[0][ni]);
            acc[1][ni] = MFMA16(af[1], bfv, acc[1][ni]);
        }
    }

    float s[2][4] = {{0.f, 0.f, 0.f, 0.f}, {0.f, 0.f, 0.f, 0.f}};
    for (int ni = 0; ni < 8; ni++) {
        int n = wv * 128 + ni * 16 + l15;
        float ub = b2f(u1b[b * 512 + n]);
        float vev = Ve[n];
        for (int mi = 0; mi < 2; mi++)
            for (int r = 0; r < 4; r++)
                s[mi][r] += vev * tanh_(acc[mi][ni][r] + ub);
    }
    for (int off = 1; off <= 8; off <<= 1)
        for (int mi = 0; mi < 2; mi++)
            for (int r = 0; r < 4; r++) s[mi][r] += __shfl_xor(s[mi][r], off);
    if (l15 == 0)
        for (int mi = 0; mi < 2; mi++)
            for (int r = 0; r < 4; r++) ered[wv][mi * 16 + q * 4 + r] = s[mi][r];
    __syncthreads();
    if (tid < 32)
        e[(long long)b * 512 + t0 + tid] =
            ered[0][tid] + ered[1][tid] + ered[2][tid] + ered[3][tid];
}

// ---------------------------------------------------------------------------
// attn_out: softmax over T, context = alpha.h, head -> mu, sigma. 1 WG per b.
// h loads packed (uint = 2 bf16), thread owns hid pair (2*tid, 2*tid+1).
// ---------------------------------------------------------------------------
__global__ __launch_bounds__(256) void attn_out(
    const float* __restrict__ e, const unsigned short* __restrict__ h_all,
    const float* __restrict__ Wout, const float* __restrict__ bout,
    float* __restrict__ outp)
{
    __shared__ float sm[512];
    __shared__ float red[8];
    const int b = blockIdx.x, tid = threadIdx.x;
    const int wv = tid >> 6, lane = tid & 63;

    float e0 = e[b * 512 + tid], e1 = e[b * 512 + 256 + tid];
    float mx = fmaxf(e0, e1);
    for (int off = 32; off; off >>= 1) mx = fmaxf(mx, __shfl_xor(mx, off));
    if (lane == 0) red[wv] = mx;
    __syncthreads();
    mx = fmaxf(fmaxf(red[0], red[1]), fmaxf(red[2], red[3]));

    float s0 = __expf(e0 - mx), s1 = __expf(e1 - mx);
    sm[tid] = s0; sm[256 + tid] = s1;
    float ss = s0 + s1;
    for (int off = 32; off; off >>= 1) ss += __shfl_xor(ss, off);
    if (lane == 0) red[4 + wv] = ss;
    __syncthreads();
    float inv = 1.0f / (red[4] + red[5] + red[6] + red[7]);

    const unsigned int* hp = (const unsigned int*)(h_all + (long long)b * 262144);
    float a0 = 0.f, a1 = 0.f;
    for (int t = 0; t < 512; t += 4) {
        #pragma unroll
        for (int j = 0; j < 4; j++) {
            float al = sm[t + j];
            unsigned v = hp[(t + j) * 256 + tid];
            a0 += al * b2f((unsigned short)(v & 0xFFFFu));
            a1 += al * b2f((unsigned short)(v >> 16));
        }
    }
    a0 *= inv; a1 *= inv;

    float q0 = a0 * Wout[2 * tid] + a1 * Wout[2 * tid + 1];
    float q1 = a0 * Wout[512 + 2 * tid] + a1 * Wout[512 + 2 * tid + 1];
    for (int off = 32; off; off >>= 1) { q0 += __shfl_xor(q0, off); q1 += __shfl_xor(q1, off); }
    __syncthreads();  // red reuse
    if (lane == 0) { red[wv] = q0; red[4 + wv] = q1; }
    __syncthreads();
    if (tid == 0) {
        float P0 = red[0] + red[1] + red[2] + red[3] + bout[0];
        float P1 = red[4] + red[5] + red[6] + red[7] + bout[1];
        outp[b] = P0;
        float sp = (P1 > 15.0f) ? P1 : log1pf(__expf(P1));
        outp[128 + b] = sp + 1e-5f;
    }
}

// ---------------------------------------------------------------------------
extern "C" void kernel_launch(void* const* d_in, const int* in_sizes, int n_in,
                              void* d_out, int out_size, void* d_ws, size_t ws_size,
                              hipStream_t stream)
{
    const float* x    = (const float*)d_in[0];
    const float* Wih  = (const float*)d_in[1];
    const float* Whh  = (const float*)d_in[2];
    const float* bih  = (const float*)d_in[3];
    const float* bhh  = (const float*)d_in[4];
    const float* Ve   = (const float*)d_in[5];
    const float* U1   = (const float*)d_in[6];
    const float* U2   = (const float*)d_in[7];
    const float* Wout = (const float*)d_in[8];
    const float* bout = (const float*)d_in[9];
    float* out = (float*)d_out;

    char* ws = (char*)d_ws;
    size_t off = 0;
    auto alloc = [&](size_t bytes) -> void* {
        void* p = ws + off;
        off += (bytes + 255) & ~(size_t)255;
        return p;
    };
    unsigned short* x_bf   = (unsigned short*)alloc(33554432ull * 2);
    unsigned short* Wih_bf = (unsigned short*)alloc(1048576ull * 2);
    unsigned short* Whh_bf = (unsigned short*)alloc(1048576ull * 2);
    unsigned short* U1a    = (unsigned short*)alloc(262144ull * 2);
    unsigned short* U1b    = (unsigned short*)alloc(262144ull * 2);
    unsigned short* U2b    = (unsigned short*)alloc(262144ull * 2);
    float*          bias   = (float*)alloc(2048ull * 4);
    unsigned short* xg     = (unsigned short*)alloc(134217728ull * 2);
    unsigned short* h_all  = (unsigned short*)alloc(33554432ull * 2);
    unsigned short* u1bv   = (unsigned short*)alloc(65536ull * 2);
    float*          e      = (float*)alloc(65536ull * 4);
    unsigned int*   ring   = (unsigned int*)alloc(131072ull * 4);  // 2x128x512 tagged
    int*            done   = (int*)alloc(256ull);
    if (off > ws_size) return;  // workspace too small: fail safe (no corruption)

    hipMemsetAsync(done, 0, 4, stream);
    prep<<<4096, 256, 0, stream>>>(x, Wih, Whh, bih, bhh, U1, U2,
                                   x_bf, Wih_bf, Whh_bf, U1a, U1b, U2b, bias);
    // xg for t<128 only (ti=0): m0 = b*512, 2048 WGs
    gemm_bt<<<dim3(128, 16), 256, 0, stream>>>(x_bf, 512, Wih_bf, 512,
                                               xg, 2048, bias, 1, 512);
    // mega: 64 lstm WGs + 6144 gemm WGs (xg for t in [128,512))
    mega<<<64 + GEMM_WGS, 256, 0, stream>>>(xg, Whh_bf, h_all, ring,
                                            x_bf, Wih_bf, bias, xg, done);
    // u1b = h_last @ U1b^T
    gemm_bt<<<dim3(1, 4), 256, 0, stream>>>(h_all + 511 * 512, 262144, U1b, 512,
                                            u1bv, 512, nullptr, 0, 128);
    attn_e<<<2048, 256, 0, stream>>>(h_all, x_bf, U1a, U2b, u1bv, Ve, e);
    attn_out<<<128, 256, 0, stream>>>(e, h_all, Wout, bout, out);
}